// Round 3
// baseline (5502.285 us; speedup 1.0000x reference)
//
#include <hip/hip_runtime.h>

typedef unsigned short u16;

#define N_ROWS 500000
#define N_STRIPS 31250   // N_ROWS / 16, exact

// ---------------- d_ws layout ----------------
// [0..64)  : int flag (0 = data is bf16, 1 = data is fp32)
// [64..)   : fp32 weights, natural [K][C] row-major, layers L0..L12 concatenated
#define WS_PACK_OFF_BYTES 64
#define W_TOTAL 87552   // floats

// Layer order: L0 in(16x32), L1 enc1(32x32), L2 enc2(32x64), L3 enc3(64x128),
// L4 lat3(128x128), L5 merge3(256x128), L6 up3(128x64), L7 lat2(64x64),
// L8 merge2(128x64), L9 up2(64x32), L10 lat1(32x32), L11 merge1(64x32), L12 up1(32x32)
#define WOFF0  0
#define WOFF1  512
#define WOFF2  1536
#define WOFF3  3584
#define WOFF4  11776
#define WOFF5  28160
#define WOFF6  60928
#define WOFF7  69120
#define WOFF8  73216
#define WOFF9  81408
#define WOFF10 83456
#define WOFF11 84480
#define WOFF12 86528

__device__ __forceinline__ u16 f2bf(float f) {
  unsigned u = __float_as_uint(f);
  u += 0x7fffu + ((u >> 16) & 1u);   // round-to-nearest-even
  return (u16)(u >> 16);
}
__device__ __forceinline__ float bf2f(u16 b) { return __uint_as_float(((unsigned)b) << 16); }

// ---------------- dtype detection (verified working in R2) ----------------
__global__ __launch_bounds__(256) void detect_dtype(const u16* __restrict__ wbits,
                                                    int* __restrict__ flag) {
  __shared__ int bad;
  if (threadIdx.x == 0) bad = 0;
  __syncthreads();
  float v = __uint_as_float(((unsigned)wbits[threadIdx.x]) << 16);
  if (!(v == v) || fabsf(v) > 1e6f) atomicAdd(&bad, 1);
  __syncthreads();
  if (threadIdx.x == 0) *flag = (bad > 8) ? 1 : 0;
}

// ---------------- weight dtype-normalization (no reordering) ----------------
__global__ __launch_bounds__(256) void pack_norm(
    const void* w0, const void* w1, const void* w2, const void* w3, const void* w4,
    const void* w5, const void* w6, const void* w7, const void* w8, const void* w9,
    const void* w10, const void* w11, const void* w12,
    const int* __restrict__ flag, float* __restrict__ wf)
{
  const void* ws[13] = {w0,w1,w2,w3,w4,w5,w6,w7,w8,w9,w10,w11,w12};
  const int OFF[13] = {WOFF0,WOFF1,WOFF2,WOFF3,WOFF4,WOFF5,WOFF6,
                       WOFF7,WOFF8,WOFF9,WOFF10,WOFF11,WOFF12};
  int i = blockIdx.x * 256 + threadIdx.x;
  if (i >= W_TOTAL) return;
  const int is_f32 = *flag;
  int l = 0;
#pragma unroll
  for (int j = 1; j < 13; ++j) if (i >= OFF[j]) l = j;
  int idx = i - OFF[l];
  wf[i] = is_f32 ? ((const float*)ws[l])[idx] : bf2f(((const u16*)ws[l])[idx]);
}

// ---------------- scalar layer: out[row][c] = relu(act[row][:] . W[:,c]) ----------------
// Lane l: row = l&15, computes C/4 columns starting at (l>>4)*(C/4).
// EPI 0: -> dst LDS (+colb) | EPI 1: relu(mm) + cat[2c]+cat[2c+1] -> dst | EPI 2: -> global
template<int K, int C, int EPI>
__device__ __forceinline__ void layer_s(
    const float* act, int SA, const float* __restrict__ W,
    float* dst, int SD, int colb,
    const float* cat, int SC,
    float* goutf, u16* goutb, int row0, int f32out, int lane)
{
  const int row = lane & 15, quad = lane >> 4;
  constexpr int CW = C / 4;
  float acc[CW];
#pragma unroll
  for (int ci = 0; ci < CW; ++ci) acc[ci] = 0.f;
#pragma unroll 1
  for (int k0 = 0; k0 < K; k0 += 16) {
    float a[16];
#pragma unroll
    for (int j = 0; j < 16; ++j) a[j] = act[row * SA + k0 + j];
#pragma unroll
    for (int ci = 0; ci < CW; ++ci) {
      const int c = quad * CW + ci;
      float s = acc[ci];
#pragma unroll
      for (int j = 0; j < 16; ++j) s += a[j] * W[(k0 + j) * C + c];
      acc[ci] = s;
    }
  }
#pragma unroll
  for (int ci = 0; ci < CW; ++ci) {
    const int c = quad * CW + ci;
    float v = acc[ci] > 0.f ? acc[ci] : 0.f;   // relu on the matmul result
    if (EPI == 0) {
      dst[row * SD + colb + c] = v;
    } else if (EPI == 1) {
      dst[row * SD + c] = v + cat[row * SC + 2 * c] + cat[row * SC + 2 * c + 1];
    } else {
      if (f32out) goutf[(size_t)(row0 + row) * 32 + c] = v;
      else        goutb[(size_t)(row0 + row) * 32 + c] = f2bf(v);
    }
  }
}

__global__ __launch_bounds__(128) void backbone_s(
    const void* __restrict__ feat, const float* __restrict__ wf,
    const int* __restrict__ flag, void* __restrict__ out)
{
  // per-wave fp32 arena: E1[16][32] | E2[16][64] | CT[16][256] | MR[16][128] = 7680 f32
  __shared__ float lds[2 * 7680];   // 61440 B
  const int lane = threadIdx.x & 63;
  const int wv   = threadIdx.x >> 6;
  const int strip = blockIdx.x * 2 + wv;
  if (strip >= N_STRIPS) return;
  const int is_f32 = *flag;

  float* S  = lds + wv * 7680;
  float* E1 = S;          // stride 32
  float* E2 = S + 512;    // stride 64
  float* CT = S + 1536;   // stride 256
  float* MR = S + 5632;   // stride 128

  const int row = lane & 15, quad = lane >> 4;
  const int row0 = strip * 16;
  float* gof = (float*)out;
  u16*   gob = (u16*)out;

  // stage feat strip into MR[:,0:16] (MR free at this point)
#pragma unroll
  for (int j = 0; j < 4; ++j) {
    const int k = quad * 4 + j;
    float v = is_f32 ? ((const float*)feat)[(size_t)(row0 + row) * 16 + k]
                     : bf2f(((const u16*)feat)[(size_t)(row0 + row) * 16 + k]);
    MR[row * 128 + k] = v;
  }

  // L0:  x0   = relu(feat @ W_in)        -> CT[:,0:32]
  layer_s<16,32,0>(MR,128, wf+WOFF0, CT,256,0,   nullptr,0, nullptr,nullptr,0,0, lane);
  // L1:  e1   = relu(x0 @ W_enc1)        -> E1
  layer_s<32,32,0>(CT,256, wf+WOFF1, E1,32,0,    nullptr,0, nullptr,nullptr,0,0, lane);
  // L2:  e2   = relu(e1 @ W_enc2)        -> E2
  layer_s<32,64,0>(E1,32,  wf+WOFF2, E2,64,0,    nullptr,0, nullptr,nullptr,0,0, lane);
  // L3:  e3   = relu(e2 @ W_enc3)        -> CT[:,0:128]
  layer_s<64,128,0>(E2,64, wf+WOFF3, CT,256,0,   nullptr,0, nullptr,nullptr,0,0, lane);
  // L4:  lat3 = relu(e3 @ W_lat3)        -> CT[:,128:256]  (reads cols<128, writes >=128)
  layer_s<128,128,0>(CT,256, wf+WOFF4, CT,256,128, nullptr,0, nullptr,nullptr,0,0, lane);
  // L5:  mr3  = relu(cat3 @ W_merge3) + red(cat3) -> MR[:,0:128]
  layer_s<256,128,1>(CT,256, wf+WOFF5, MR,128,0,  CT,256,    nullptr,nullptr,0,0, lane);
  // L6:  x2   = relu(mr3 @ W_up3)        -> CT[:,0:64]
  layer_s<128,64,0>(MR,128, wf+WOFF6, CT,256,0,  nullptr,0, nullptr,nullptr,0,0, lane);
  // L7:  lat2 = relu(e2 @ W_lat2)        -> CT[:,64:128]
  layer_s<64,64,0>(E2,64,  wf+WOFF7, CT,256,64,  nullptr,0, nullptr,nullptr,0,0, lane);
  // L8:  mr2  = relu(cat2 @ W_merge2) + red(cat2) -> MR[:,0:64]
  layer_s<128,64,1>(CT,256, wf+WOFF8, MR,128,0,  CT,256,    nullptr,nullptr,0,0, lane);
  // L9:  x1   = relu(mr2 @ W_up2)        -> CT[:,0:32]
  layer_s<64,32,0>(MR,128, wf+WOFF9, CT,256,0,   nullptr,0, nullptr,nullptr,0,0, lane);
  // L10: lat1 = relu(e1 @ W_lat1)        -> CT[:,32:64]
  layer_s<32,32,0>(E1,32,  wf+WOFF10, CT,256,32, nullptr,0, nullptr,nullptr,0,0, lane);
  // L11: mr1  = relu(cat1 @ W_merge1) + red(cat1) -> MR[:,0:32]
  layer_s<64,32,1>(CT,256, wf+WOFF11, MR,128,0,  CT,256,    nullptr,nullptr,0,0, lane);
  // L12: out  = relu(mr1 @ W_up1)        -> global [N,32]
  layer_s<32,32,2>(MR,128, wf+WOFF12, nullptr,0,0, nullptr,0, gof,gob,row0,is_f32, lane);
}

extern "C" void kernel_launch(void* const* d_in, const int* in_sizes, int n_in,
                              void* d_out, int out_size, void* d_ws, size_t ws_size,
                              hipStream_t stream) {
  (void)in_sizes; (void)n_in; (void)out_size; (void)ws_size;
  int* flag = (int*)d_ws;
  float* wf = (float*)((char*)d_ws + WS_PACK_OFF_BYTES);

  hipLaunchKernelGGL(detect_dtype, dim3(1), dim3(256), 0, stream,
                     (const u16*)d_in[2], flag);

  // order: in, enc1, enc2, enc3, lat3, merge3, up3, lat2, merge2, up2, lat1, merge1, up1
  hipLaunchKernelGGL(pack_norm, dim3((W_TOTAL + 255) / 256), dim3(256), 0, stream,
      d_in[2],  d_in[3],  d_in[4],  d_in[5],  d_in[8],  d_in[11], d_in[14],
      d_in[7],  d_in[10], d_in[13], d_in[6],  d_in[9],  d_in[12],
      (const int*)flag, wf);

  hipLaunchKernelGGL(backbone_s, dim3(N_STRIPS / 2), dim3(128), 0, stream,
                     (const void*)d_in[0], (const float*)wf, (const int*)flag, d_out);
}

// Round 6
// 786.897 us; speedup vs baseline: 6.9924x; 6.9924x over previous
//
#include <hip/hip_runtime.h>

typedef unsigned short u16;
typedef _Float16 h16;
typedef __attribute__((ext_vector_type(8))) _Float16 half8;
typedef __attribute__((ext_vector_type(8))) unsigned short ushort8;
typedef __attribute__((ext_vector_type(4))) float f32x4;

#define N_STRIPS 31250          // 500000 / 16
#define NPAIRS   15625          // blocks; each block = 1 wave = 2 strips (M=32)
#define STRIP    16384          // h16 offset between the two strip arenas

// compiler-level memory ordering fence (zero instructions; per-wave DS ops are
// in-order in HW, so source order == correctness once the compiler keeps it)
#define MEMBAR() asm volatile("" ::: "memory")

// ---------------- packed weight frag-pairs (f16 hi/lo) ----------------
// fragpair f (layer-local index ct*KT+kt), lane l, 32 B each:
//   wp[(f*64+l)*16 + j]   = hi = f16(W[k][col])        (j=0..7)
//   wp[(f*64+l)*16 + 8+j] = lo = f16(W - (float)hi)
// k = kt*32 + (l>>4)*8 + j, col = ct*16 + (l&15); zero-pad k >= K_actual.
// Layer order: L0 in, L1 enc1, L2 enc2, L3 enc3, L4 lat3, L5 merge3, L6 up3,
//              L7 lat2, L8 merge2, L9 up2, L10 lat1, L11 merge1, L12 up1
#define F_L0   0
#define F_L1   2
#define F_L2   4
#define F_L3   8
#define F_L4   24
#define F_L5   56
#define F_L6   120
#define F_L7   136
#define F_L8   144
#define F_L9   160
#define F_L10  164
#define F_L11  166
#define F_L12  170
#define NFRAG  172              // d_ws bytes: 172*1024*2 = 352256

__device__ __forceinline__ u16 hb(h16 h) { union { h16 h; u16 u; } v; v.h = h; return v.u; }

// ---------------- weight packing (fp32 -> f16 hi/lo fragpairs) ----------------
__global__ __launch_bounds__(256) void pack_w(
    const float* w0, const float* w1, const float* w2, const float* w3, const float* w4,
    const float* w5, const float* w6, const float* w7, const float* w8, const float* w9,
    const float* w10, const float* w11, const float* w12, u16* __restrict__ packed)
{
  const float* ws[13] = {w0,w1,w2,w3,w4,w5,w6,w7,w8,w9,w10,w11,w12};
  const int Ka[13]  = {16,32,32,64,128,256,128,64,128,64,32,64,32};
  const int KT[13]  = {1,1,1,2,4,8,4,2,4,2,1,2,1};
  const int CO[13]  = {32,32,64,128,128,128,64,64,64,32,32,32,32};
  const int FO[13]  = {F_L0,F_L1,F_L2,F_L3,F_L4,F_L5,F_L6,F_L7,F_L8,F_L9,F_L10,F_L11,F_L12};
  int g = blockIdx.x * 256 + threadIdx.x;
  int f = g >> 6, lane = g & 63;
  if (f >= NFRAG) return;
  int layer = 0;
#pragma unroll
  for (int i = 1; i < 13; ++i) if (f >= FO[i]) layer = i;
  int fl = f - FO[layer];
  int kt = fl % KT[layer];
  int ct = fl / KT[layer];
  int cout = CO[layer];
  int quad = lane >> 4;
  int col  = ct * 16 + (lane & 15);
  u16 thi[8], tlo[8];
#pragma unroll
  for (int j = 0; j < 8; ++j) {
    int k = kt * 32 + quad * 8 + j;
    float w = (k < Ka[layer]) ? ws[layer][k * cout + col] : 0.f;
    h16 h = (h16)w;
    h16 l = (h16)(w - (float)h);
    thi[j] = hb(h); tlo[j] = hb(l);
  }
  u16* dst = packed + ((size_t)f * 64 + lane) * 16;
  *(ushort8*)dst       = *(const ushort8*)thi;
  *(ushort8*)(dst + 8) = *(const ushort8*)tlo;
}

// ---------------- fused backbone, M=32 (2 strips / wave) ----------------
// Per-strip arena (h16), hi plane at base, lo plane at base + 16*stride:
//   E1 @ 0     str 40  (2*640)   | E2 @ 1280  str 72  (2*1152)
//   CT @ 3584  str 264 (2*4224)  | MR @ 12032 str 136 (2*2176)   total 16384

template<int KT>
__device__ __forceinline__ void loadA2(const h16* __restrict__ pH, int stride, int lane,
                                       half8* ah0, half8* al0, half8* ah1, half8* al1)
{
  const int base = (lane & 15) * stride + (lane >> 4) * 8;
  const int lo = 16 * stride;
#pragma unroll
  for (int kt = 0; kt < KT; ++kt) {
    ah0[kt] = *(const half8*)(pH + base + kt * 32);
    al0[kt] = *(const half8*)(pH + lo + base + kt * 32);
    ah1[kt] = *(const half8*)(pH + STRIP + base + kt * 32);
    al1[kt] = *(const half8*)(pH + STRIP + lo + base + kt * 32);
  }
}

__device__ __forceinline__ void splitw(h16* dst, int idx, int lo, float v) {
  h16 h = (h16)v;
  dst[idx]      = h;
  dst[idx + lo] = (h16)(v - (float)h);
}
__device__ __forceinline__ float red4(const h16* cat, int cs, int rr, int cc) {
  const h16* p = cat + rr * cs + 2 * cc;
  const h16* q = p + 16 * cs;
  return (float)p[0] + (float)p[1] + (float)q[0] + (float)q[1];
}

// EPI 0: relu -> hi/lo planes (+colb) | EPI 1: relu + pairwise-red(cat) -> planes
// EPI 2: relu -> global fp32 [N,32]
template<int KT, int COT, int EPI>
__device__ __forceinline__ void layer2(
    const half8* ah0, const half8* al0, const half8* ah1, const half8* al1,
    const h16* __restrict__ wp, int lane,
    h16* dst, int ds, int colb,
    const h16* cat, int cs,
    float* __restrict__ gout, int row0)
{
  const int l15 = lane & 15, quad = lane >> 4;
  const int dlo = 16 * ds;
#pragma unroll
  for (int ct = 0; ct < COT; ++ct) {
    f32x4 a0 = {0.f,0.f,0.f,0.f}, a1 = {0.f,0.f,0.f,0.f};
#pragma unroll
    for (int kt = 0; kt < KT; ++kt) {
      const h16* fp = wp + (((size_t)(ct * KT + kt)) * 64 + lane) * 16;
      half8 bhv = *(const half8*)fp;
      half8 blv = *(const half8*)(fp + 8);
      a0 = __builtin_amdgcn_mfma_f32_16x16x32_f16(al0[kt], bhv, a0, 0, 0, 0);
      a0 = __builtin_amdgcn_mfma_f32_16x16x32_f16(ah0[kt], blv, a0, 0, 0, 0);
      a0 = __builtin_amdgcn_mfma_f32_16x16x32_f16(ah0[kt], bhv, a0, 0, 0, 0);
      a1 = __builtin_amdgcn_mfma_f32_16x16x32_f16(al1[kt], bhv, a1, 0, 0, 0);
      a1 = __builtin_amdgcn_mfma_f32_16x16x32_f16(ah1[kt], blv, a1, 0, 0, 0);
      a1 = __builtin_amdgcn_mfma_f32_16x16x32_f16(ah1[kt], bhv, a1, 0, 0, 0);
    }
#pragma unroll
    for (int r = 0; r < 4; ++r) {
      const int rr = quad * 4 + r;
      const int cc = ct * 16 + l15;
      float v0 = a0[r] > 0.f ? a0[r] : 0.f;
      float v1 = a1[r] > 0.f ? a1[r] : 0.f;
      if (EPI == 1) {
        v0 += red4(cat, cs, rr, cc);
        v1 += red4(cat + STRIP, cs, rr, cc);
      }
      if (EPI <= 1) {
        splitw(dst,         rr * ds + colb + cc, dlo, v0);
        splitw(dst + STRIP, rr * ds + colb + cc, dlo, v1);
      } else {
        gout[(size_t)(row0 + rr) * 32 + cc]      = v0;
        gout[(size_t)(row0 + 16 + rr) * 32 + cc] = v1;
      }
    }
  }
}

__global__ __launch_bounds__(64, 1) void backbone(
    const float* __restrict__ feat, const h16* __restrict__ wp, float* __restrict__ out)
{
  __shared__ h16 lds[2 * STRIP];   // 65536 B: two strip arenas
  const int lane = threadIdx.x;
  const int l15 = lane & 15, quad = lane >> 4;
  const int row0 = blockIdx.x * 32;

  h16* E1 = lds;            const int SE1 = 40;
  h16* E2 = lds + 1280;     const int SE2 = 72;
  h16* CT = lds + 3584;     const int SCT = 264;
  h16* MR = lds + 12032;    const int SMR = 136;

  half8 ah0[8], al0[8], ah1[8], al1[8];

  // L0: A from feat (K=16 pad 32): quads 0-1 real, 2-3 zero
  {
    h16 th0[8] = {0,0,0,0,0,0,0,0}, tl0[8] = {0,0,0,0,0,0,0,0};
    h16 th1[8] = {0,0,0,0,0,0,0,0}, tl1[8] = {0,0,0,0,0,0,0,0};
    if (quad < 2) {
      const float* s0 = feat + (size_t)(row0 + l15) * 16 + quad * 8;
      const float* s1 = feat + (size_t)(row0 + 16 + l15) * 16 + quad * 8;
#pragma unroll
      for (int j = 0; j < 8; ++j) {
        float v0 = s0[j], v1 = s1[j];
        h16 h0 = (h16)v0, h1 = (h16)v1;
        th0[j] = h0; tl0[j] = (h16)(v0 - (float)h0);
        th1[j] = h1; tl1[j] = (h16)(v1 - (float)h1);
      }
    }
    ah0[0] = *(const half8*)th0; al0[0] = *(const half8*)tl0;
    ah1[0] = *(const half8*)th1; al1[0] = *(const half8*)tl1;
  }
  layer2<1,2,0>(ah0,al0,ah1,al1, wp + F_L0*1024, lane, CT,SCT,0, nullptr,0, nullptr,0);
  MEMBAR();
  loadA2<1>(CT,SCT,lane, ah0,al0,ah1,al1);   // L1: x0 -> E1
  layer2<1,2,0>(ah0,al0,ah1,al1, wp + F_L1*1024, lane, E1,SE1,0, nullptr,0, nullptr,0);
  MEMBAR();
  loadA2<1>(E1,SE1,lane, ah0,al0,ah1,al1);   // L2: e1 -> E2
  layer2<1,4,0>(ah0,al0,ah1,al1, wp + F_L2*1024, lane, E2,SE2,0, nullptr,0, nullptr,0);
  MEMBAR();
  loadA2<2>(E2,SE2,lane, ah0,al0,ah1,al1);   // L3: e2 -> CT[:,0:128]
  layer2<2,8,0>(ah0,al0,ah1,al1, wp + F_L3*1024, lane, CT,SCT,0, nullptr,0, nullptr,0);
  MEMBAR();
  loadA2<4>(CT,SCT,lane, ah0,al0,ah1,al1);   // L4: e3 -> CT[:,128:256]
  layer2<4,8,0>(ah0,al0,ah1,al1, wp + F_L4*1024, lane, CT,SCT,128, nullptr,0, nullptr,0);
  MEMBAR();
  loadA2<8>(CT,SCT,lane, ah0,al0,ah1,al1);   // L5: merge3+red -> MR[:,0:128]
  layer2<8,8,1>(ah0,al0,ah1,al1, wp + F_L5*1024, lane, MR,SMR,0, CT,SCT, nullptr,0);
  MEMBAR();
  loadA2<4>(MR,SMR,lane, ah0,al0,ah1,al1);   // L6: x2 -> CT[:,0:64]
  layer2<4,4,0>(ah0,al0,ah1,al1, wp + F_L6*1024, lane, CT,SCT,0, nullptr,0, nullptr,0);
  MEMBAR();
  loadA2<2>(E2,SE2,lane, ah0,al0,ah1,al1);   // L7: lat2 -> CT[:,64:128]
  layer2<2,4,0>(ah0,al0,ah1,al1, wp + F_L7*1024, lane, CT,SCT,64, nullptr,0, nullptr,0);
  MEMBAR();
  loadA2<4>(CT,SCT,lane, ah0,al0,ah1,al1);   // L8: merge2+red -> MR[:,0:64]
  layer2<4,4,1>(ah0,al0,ah1,al1, wp + F_L8*1024, lane, MR,SMR,0, CT,SCT, nullptr,0);
  MEMBAR();
  loadA2<2>(MR,SMR,lane, ah0,al0,ah1,al1);   // L9: x1 -> CT[:,0:32]
  layer2<2,2,0>(ah0,al0,ah1,al1, wp + F_L9*1024, lane, CT,SCT,0, nullptr,0, nullptr,0);
  MEMBAR();
  loadA2<1>(E1,SE1,lane, ah0,al0,ah1,al1);   // L10: lat1 -> CT[:,32:64]
  layer2<1,2,0>(ah0,al0,ah1,al1, wp + F_L10*1024, lane, CT,SCT,32, nullptr,0, nullptr,0);
  MEMBAR();
  loadA2<2>(CT,SCT,lane, ah0,al0,ah1,al1);   // L11: merge1+red -> MR[:,0:32]
  layer2<2,2,1>(ah0,al0,ah1,al1, wp + F_L11*1024, lane, MR,SMR,0, CT,SCT, nullptr,0);
  MEMBAR();
  loadA2<1>(MR,SMR,lane, ah0,al0,ah1,al1);   // L12: out -> global fp32 [N,32]
  layer2<1,2,2>(ah0,al0,ah1,al1, wp + F_L12*1024, lane, nullptr,0,0, nullptr,0, out, row0);
}

extern "C" void kernel_launch(void* const* d_in, const int* in_sizes, int n_in,
                              void* d_out, int out_size, void* d_ws, size_t ws_size,
                              hipStream_t stream) {
  (void)in_sizes; (void)n_in; (void)out_size; (void)ws_size;
  u16* packed = (u16*)d_ws;   // 352256 B

  // order: in, enc1, enc2, enc3, lat3, merge3, up3, lat2, merge2, up2, lat1, merge1, up1
  hipLaunchKernelGGL(pack_w, dim3(43), dim3(256), 0, stream,
      (const float*)d_in[2],  (const float*)d_in[3],  (const float*)d_in[4],
      (const float*)d_in[5],  (const float*)d_in[8],  (const float*)d_in[11],
      (const float*)d_in[14], (const float*)d_in[7],  (const float*)d_in[10],
      (const float*)d_in[13], (const float*)d_in[6],  (const float*)d_in[9],
      (const float*)d_in[12], packed);

  hipLaunchKernelGGL(backbone, dim3(NPAIRS), dim3(64), 0, stream,
                     (const float*)d_in[0], (const h16*)packed, (float*)d_out);
}

// Round 7
// 478.390 us; speedup vs baseline: 11.5017x; 1.6449x over previous
//
#include <hip/hip_runtime.h>

typedef unsigned short u16;
typedef _Float16 h16;
typedef __attribute__((ext_vector_type(8))) _Float16 half8;
typedef __attribute__((ext_vector_type(8))) unsigned short ushort8;
typedef __attribute__((ext_vector_type(4))) float f32x4;

#define N_STRIPS 31250          // 500000 / 16
#define NPAIRS   15625          // blocks; each block = 4 waves = 2 strips (M=32)
#define STRIP    16384          // h16 offset between the two strip arenas

// ---------------- packed weight frag-pairs (f16 hi/lo) ----------------
// fragpair f (layer-local index ct*KT+kt), lane l, 32 B each:
//   wp[(f*64+l)*16 + j]   = hi = f16(W[k][col])        (j=0..7)
//   wp[(f*64+l)*16 + 8+j] = lo = f16(W - (float)hi)
// k = kt*32 + (l>>4)*8 + j, col = ct*16 + (l&15); zero-pad k >= K_actual.
// Layer order: L0 in, L1 enc1, L2 enc2, L3 enc3, L4 lat3, L5 merge3, L6 up3,
//              L7 lat2, L8 merge2, L9 up2, L10 lat1, L11 merge1, L12 up1
#define F_L0   0
#define F_L1   2
#define F_L2   4
#define F_L3   8
#define F_L4   24
#define F_L5   56
#define F_L6   120
#define F_L7   136
#define F_L8   144
#define F_L9   160
#define F_L10  164
#define F_L11  166
#define F_L12  170
#define NFRAG  172              // d_ws bytes: 172*1024*2 = 352256

__device__ __forceinline__ u16 hb(h16 h) { union { h16 h; u16 u; } v; v.h = h; return v.u; }

// ---------------- weight packing (fp32 -> f16 hi/lo fragpairs) ----------------
__global__ __launch_bounds__(256) void pack_w(
    const float* w0, const float* w1, const float* w2, const float* w3, const float* w4,
    const float* w5, const float* w6, const float* w7, const float* w8, const float* w9,
    const float* w10, const float* w11, const float* w12, u16* __restrict__ packed)
{
  const float* ws[13] = {w0,w1,w2,w3,w4,w5,w6,w7,w8,w9,w10,w11,w12};
  const int Ka[13]  = {16,32,32,64,128,256,128,64,128,64,32,64,32};
  const int KT[13]  = {1,1,1,2,4,8,4,2,4,2,1,2,1};
  const int CO[13]  = {32,32,64,128,128,128,64,64,64,32,32,32,32};
  const int FO[13]  = {F_L0,F_L1,F_L2,F_L3,F_L4,F_L5,F_L6,F_L7,F_L8,F_L9,F_L10,F_L11,F_L12};
  int g = blockIdx.x * 256 + threadIdx.x;
  int f = g >> 6, lane = g & 63;
  if (f >= NFRAG) return;
  int layer = 0;
#pragma unroll
  for (int i = 1; i < 13; ++i) if (f >= FO[i]) layer = i;
  int fl = f - FO[layer];
  int kt = fl % KT[layer];
  int ct = fl / KT[layer];
  int cout = CO[layer];
  int quad = lane >> 4;
  int col  = ct * 16 + (lane & 15);
  u16 thi[8], tlo[8];
#pragma unroll
  for (int j = 0; j < 8; ++j) {
    int k = kt * 32 + quad * 8 + j;
    float w = (k < Ka[layer]) ? ws[layer][k * cout + col] : 0.f;
    h16 h = (h16)w;
    h16 l = (h16)(w - (float)h);
    thi[j] = hb(h); tlo[j] = hb(l);
  }
  u16* dst = packed + ((size_t)f * 64 + lane) * 16;
  *(ushort8*)dst       = *(const ushort8*)thi;
  *(ushort8*)(dst + 8) = *(const ushort8*)tlo;
}

// ---------------- fused backbone, M=32, 4 waves split the ct loop ----------------
// Shared arena (h16), hi plane at base, lo plane at base + 16*stride:
//   E1 @ 0     str 40  (2*640)   | E2 @ 1280  str 72  (2*1152)
//   CT @ 3584  str 264 (2*4224)  | MR @ 12032 str 136 (2*2176)   = 16384/strip

template<int KT>
__device__ __forceinline__ void loadA2(const h16* __restrict__ pH, int stride, int lane,
                                       half8* ah0, half8* al0, half8* ah1, half8* al1)
{
  const int base = (lane & 15) * stride + (lane >> 4) * 8;
  const int lo = 16 * stride;
#pragma unroll
  for (int kt = 0; kt < KT; ++kt) {
    ah0[kt] = *(const half8*)(pH + base + kt * 32);
    al0[kt] = *(const half8*)(pH + lo + base + kt * 32);
    ah1[kt] = *(const half8*)(pH + STRIP + base + kt * 32);
    al1[kt] = *(const half8*)(pH + STRIP + lo + base + kt * 32);
  }
}

__device__ __forceinline__ void splitw(h16* dst, int idx, int lo, float v) {
  h16 h = (h16)v;
  dst[idx]      = h;
  dst[idx + lo] = (h16)(v - (float)h);
}
__device__ __forceinline__ float red4(const h16* cat, int cs, int rr, int cc) {
  const h16* p = cat + rr * cs + 2 * cc;
  const h16* q = p + 16 * cs;
  return (float)p[0] + (float)p[1] + (float)q[0] + (float)q[1];
}

// EPI 0: relu -> hi/lo planes (+colb) | EPI 1: relu + pairwise-red(cat) -> planes
// EPI 2: relu -> global fp32 [N,32]. CN = #ct tiles this wave; cb = first ct.
template<int KT, int CN, int EPI>
__device__ __forceinline__ void layer2(
    const half8* ah0, const half8* al0, const half8* ah1, const half8* al1,
    const h16* __restrict__ wp, int lane, int cb,
    h16* dst, int ds, int colb,
    const h16* cat, int cs,
    float* __restrict__ gout, int row0)
{
  const int l15 = lane & 15, quad = lane >> 4;
  const int dlo = 16 * ds;
#pragma unroll
  for (int ci = 0; ci < CN; ++ci) {
    const int ct = cb + ci;
    f32x4 a0 = {0.f,0.f,0.f,0.f}, a1 = {0.f,0.f,0.f,0.f};
#pragma unroll
    for (int kt = 0; kt < KT; ++kt) {
      const h16* fp = wp + (((size_t)(ct * KT + kt)) * 64 + lane) * 16;
      half8 bhv = *(const half8*)fp;
      half8 blv = *(const half8*)(fp + 8);
      a0 = __builtin_amdgcn_mfma_f32_16x16x32_f16(al0[kt], bhv, a0, 0, 0, 0);
      a0 = __builtin_amdgcn_mfma_f32_16x16x32_f16(ah0[kt], blv, a0, 0, 0, 0);
      a0 = __builtin_amdgcn_mfma_f32_16x16x32_f16(ah0[kt], bhv, a0, 0, 0, 0);
      a1 = __builtin_amdgcn_mfma_f32_16x16x32_f16(al1[kt], bhv, a1, 0, 0, 0);
      a1 = __builtin_amdgcn_mfma_f32_16x16x32_f16(ah1[kt], blv, a1, 0, 0, 0);
      a1 = __builtin_amdgcn_mfma_f32_16x16x32_f16(ah1[kt], bhv, a1, 0, 0, 0);
    }
#pragma unroll
    for (int r = 0; r < 4; ++r) {
      const int rr = quad * 4 + r;
      const int cc = ct * 16 + l15;
      float v0 = a0[r] > 0.f ? a0[r] : 0.f;
      float v1 = a1[r] > 0.f ? a1[r] : 0.f;
      if (EPI == 1) {
        v0 += red4(cat, cs, rr, cc);
        v1 += red4(cat + STRIP, cs, rr, cc);
      }
      if (EPI <= 1) {
        splitw(dst,         rr * ds + colb + cc, dlo, v0);
        splitw(dst + STRIP, rr * ds + colb + cc, dlo, v1);
      } else {
        gout[(size_t)(row0 + rr) * 32 + cc]      = v0;
        gout[(size_t)(row0 + 16 + rr) * 32 + cc] = v1;
      }
    }
  }
}

// one layer: 4 waves split COT tiles (COT>=4: quarters; COT==2: waves 0,1 only)
#define LAYER(KT, COT, EPI, SRC, SS, FOFF, DST, DS, COLB, CAT, CS, GOUT, ROW0)      \
  {                                                                                  \
    constexpr int CN = ((COT) >= 4) ? (COT) / 4 : 1;                                 \
    const int cb = ((COT) >= 4) ? wv * CN : wv;                                      \
    if (((COT) >= 4) || (wv < 2)) {                                                  \
      loadA2<KT>(SRC, SS, lane, ah0, al0, ah1, al1);                                 \
      layer2<KT, CN, EPI>(ah0, al0, ah1, al1, wp + (FOFF) * 1024, lane, cb,          \
                          DST, DS, COLB, CAT, CS, GOUT, ROW0);                       \
    }                                                                                \
    __syncthreads();                                                                 \
  }

__global__ __launch_bounds__(256, 2) void backbone(
    const float* __restrict__ feat, const h16* __restrict__ wp, float* __restrict__ out)
{
  __shared__ h16 lds[2 * STRIP];   // 65536 B, shared by the block's 4 waves
  const int lane = threadIdx.x & 63;
  const int wv   = threadIdx.x >> 6;
  const int l15 = lane & 15, quad = lane >> 4;
  const int row0 = blockIdx.x * 32;

  h16* E1 = lds;            const int SE1 = 40;
  h16* E2 = lds + 1280;     const int SE2 = 72;
  h16* CT = lds + 3584;     const int SCT = 264;
  h16* MR = lds + 12032;    const int SMR = 136;

  half8 ah0[8], al0[8], ah1[8], al1[8];

  // L0: A from feat (K=16 pad 32): quads 0-1 real, 2-3 zero; waves 0,1 do ct=wv
  if (wv < 2) {
    h16 th0[8] = {0,0,0,0,0,0,0,0}, tl0[8] = {0,0,0,0,0,0,0,0};
    h16 th1[8] = {0,0,0,0,0,0,0,0}, tl1[8] = {0,0,0,0,0,0,0,0};
    if (quad < 2) {
      const float* s0 = feat + (size_t)(row0 + l15) * 16 + quad * 8;
      const float* s1 = feat + (size_t)(row0 + 16 + l15) * 16 + quad * 8;
#pragma unroll
      for (int j = 0; j < 8; ++j) {
        float v0 = s0[j], v1 = s1[j];
        h16 h0 = (h16)v0, h1 = (h16)v1;
        th0[j] = h0; tl0[j] = (h16)(v0 - (float)h0);
        th1[j] = h1; tl1[j] = (h16)(v1 - (float)h1);
      }
    }
    ah0[0] = *(const half8*)th0; al0[0] = *(const half8*)tl0;
    ah1[0] = *(const half8*)th1; al1[0] = *(const half8*)tl1;
    layer2<1,1,0>(ah0,al0,ah1,al1, wp + F_L0*1024, lane, wv, CT,SCT,0, nullptr,0,
                  nullptr,0);
  }
  __syncthreads();

  LAYER(1,2,0,  CT,SCT, F_L1,  E1,SE1,0,   nullptr,0, nullptr,0)    // L1: x0 -> E1
  LAYER(1,4,0,  E1,SE1, F_L2,  E2,SE2,0,   nullptr,0, nullptr,0)    // L2: e1 -> E2
  LAYER(2,8,0,  E2,SE2, F_L3,  CT,SCT,0,   nullptr,0, nullptr,0)    // L3: e2 -> CT[0:128]
  LAYER(4,8,0,  CT,SCT, F_L4,  CT,SCT,128, nullptr,0, nullptr,0)    // L4: e3 -> CT[128:256]
  LAYER(8,8,1,  CT,SCT, F_L5,  MR,SMR,0,   CT,SCT,   nullptr,0)     // L5: merge3+red -> MR[0:128]
  LAYER(4,4,0,  MR,SMR, F_L6,  CT,SCT,0,   nullptr,0, nullptr,0)    // L6: x2 -> CT[0:64]
  LAYER(2,4,0,  E2,SE2, F_L7,  CT,SCT,64,  nullptr,0, nullptr,0)    // L7: lat2 -> CT[64:128]
  LAYER(4,4,1,  CT,SCT, F_L8,  MR,SMR,0,   CT,SCT,   nullptr,0)     // L8: merge2+red -> MR[0:64]
  LAYER(2,2,0,  MR,SMR, F_L9,  CT,SCT,0,   nullptr,0, nullptr,0)    // L9: x1 -> CT[0:32]
  LAYER(1,2,0,  E1,SE1, F_L10, CT,SCT,32,  nullptr,0, nullptr,0)    // L10: lat1 -> CT[32:64]
  LAYER(2,2,1,  CT,SCT, F_L11, MR,SMR,0,   CT,SCT,   nullptr,0)     // L11: merge1+red -> MR[0:32]
  LAYER(1,2,2,  MR,SMR, F_L12, nullptr,0,0, nullptr,0, out,row0)    // L12: out -> global
}

extern "C" void kernel_launch(void* const* d_in, const int* in_sizes, int n_in,
                              void* d_out, int out_size, void* d_ws, size_t ws_size,
                              hipStream_t stream) {
  (void)in_sizes; (void)n_in; (void)out_size; (void)ws_size;
  u16* packed = (u16*)d_ws;   // 352256 B

  // order: in, enc1, enc2, enc3, lat3, merge3, up3, lat2, merge2, up2, lat1, merge1, up1
  hipLaunchKernelGGL(pack_w, dim3(43), dim3(256), 0, stream,
      (const float*)d_in[2],  (const float*)d_in[3],  (const float*)d_in[4],
      (const float*)d_in[5],  (const float*)d_in[8],  (const float*)d_in[11],
      (const float*)d_in[14], (const float*)d_in[7],  (const float*)d_in[10],
      (const float*)d_in[13], (const float*)d_in[6],  (const float*)d_in[9],
      (const float*)d_in[12], packed);

  hipLaunchKernelGGL(backbone, dim3(NPAIRS), dim3(256), 0, stream,
                     (const float*)d_in[0], (const h16*)packed, (float*)d_out);
}

// Round 8
// 457.506 us; speedup vs baseline: 12.0267x; 1.0456x over previous
//
#include <hip/hip_runtime.h>

typedef unsigned short u16;
typedef _Float16 h16;
typedef __attribute__((ext_vector_type(8))) _Float16 half8;
typedef __attribute__((ext_vector_type(8))) unsigned short ushort8;
typedef __attribute__((ext_vector_type(4))) float f32x4;

#define N_STRIPS 31250          // 500000 / 16
#define NPAIRS   15625          // blocks; each block = 8 waves = 2 strips (M=32)
#define STRIP    16384          // h16 offset between the two strip arenas

#define MFMA16(A,B,C) __builtin_amdgcn_mfma_f32_16x16x32_f16(A,B,C,0,0,0)

// light barrier: drain LDS ops only; global loads stay in flight (AITER pattern)
#define LBAR() asm volatile("s_waitcnt lgkmcnt(0)\n\ts_barrier" ::: "memory")

// ---------------- packed weight frag-pairs (f16 hi/lo) ----------------
// fragpair f (layer-local ct*KT+kt), lane l, 32 B:
//   wp[(f*64+l)*16 + j]   = hi = f16(W[k][col])   (j=0..7)
//   wp[(f*64+l)*16 + 8+j] = lo = f16(W - (float)hi)
// k = kt*32 + (l>>4)*8 + j, col = ct*16 + (l&15); zero-pad k >= K_actual.
// Layer order: L0 in, L1 enc1, L2 enc2, L3 enc3, L4 lat3, L5 merge3, L6 up3,
//              L7 lat2, L8 merge2, L9 up2, L10 lat1, L11 merge1, L12 up1
#define F_L0   0
#define F_L1   2
#define F_L2   4
#define F_L3   8
#define F_L4   24
#define F_L5   56
#define F_L6   120
#define F_L7   136
#define F_L8   144
#define F_L9   160
#define F_L10  164
#define F_L11  166
#define F_L12  170
#define NFRAG  172              // d_ws bytes: 172*1024*2 = 352256

__device__ __forceinline__ u16 hb(h16 h) { union { h16 h; u16 u; } v; v.h = h; return v.u; }

// ---------------- weight packing (fp32 -> f16 hi/lo fragpairs) ----------------
__global__ __launch_bounds__(256) void pack_w(
    const float* w0, const float* w1, const float* w2, const float* w3, const float* w4,
    const float* w5, const float* w6, const float* w7, const float* w8, const float* w9,
    const float* w10, const float* w11, const float* w12, u16* __restrict__ packed)
{
  const float* ws[13] = {w0,w1,w2,w3,w4,w5,w6,w7,w8,w9,w10,w11,w12};
  const int Ka[13]  = {16,32,32,64,128,256,128,64,128,64,32,64,32};
  const int KT[13]  = {1,1,1,2,4,8,4,2,4,2,1,2,1};
  const int CO[13]  = {32,32,64,128,128,128,64,64,64,32,32,32,32};
  const int FO[13]  = {F_L0,F_L1,F_L2,F_L3,F_L4,F_L5,F_L6,F_L7,F_L8,F_L9,F_L10,F_L11,F_L12};
  int g = blockIdx.x * 256 + threadIdx.x;
  int f = g >> 6, lane = g & 63;
  if (f >= NFRAG) return;
  int layer = 0;
#pragma unroll
  for (int i = 1; i < 13; ++i) if (f >= FO[i]) layer = i;
  int fl = f - FO[layer];
  int kt = fl % KT[layer];
  int ct = fl / KT[layer];
  int cout = CO[layer];
  int quad = lane >> 4;
  int col  = ct * 16 + (lane & 15);
  u16 thi[8], tlo[8];
#pragma unroll
  for (int j = 0; j < 8; ++j) {
    int k = kt * 32 + quad * 8 + j;
    float w = (k < Ka[layer]) ? ws[layer][k * cout + col] : 0.f;
    h16 h = (h16)w;
    h16 l = (h16)(w - (float)h);
    thi[j] = hb(h); tlo[j] = hb(l);
  }
  u16* dst = packed + ((size_t)f * 64 + lane) * 16;
  *(ushort8*)dst       = *(const ushort8*)thi;
  *(ushort8*)(dst + 8) = *(const ushort8*)tlo;
}

// ---------------- fused backbone: M=32, 8 waves, 1 ct-tile per wave ----------------
// Shared arena (h16), hi plane at base, lo plane at base + 16*stride:
//   E1 @ 0     str 40  | E2 @ 1280  str 72 | CT @ 3584 str 264 | MR @ 12032 str 136

__device__ __forceinline__ void splitw(h16* dst, int idx, int lo, float v) {
  h16 h = (h16)v;
  dst[idx]      = h;
  dst[idx + lo] = (h16)(v - (float)h);
}
__device__ __forceinline__ float red4(const h16* cat, int cs, int rr, int cc) {
  const h16* p = cat + rr * cs + 2 * cc;
  const h16* q = p + 16 * cs;
  return (float)p[0] + (float)p[1] + (float)q[0] + (float)q[1];
}

// EPI 0: relu -> hi/lo planes (+colb) | EPI 1: + pairwise-red(cat) | EPI 2: -> global fp32
template<int EPI>
__device__ __forceinline__ void epilogue(
    f32x4 a0, f32x4 a1, int ct, int lane,
    h16* dst, int ds, int colb, const h16* cat, int cs,
    float* __restrict__ gout, int row0)
{
  const int l15 = lane & 15, quad = lane >> 4;
  const int dlo = 16 * ds;
#pragma unroll
  for (int r = 0; r < 4; ++r) {
    const int rr = quad * 4 + r;
    const int cc = ct * 16 + l15;
    float v0 = a0[r] > 0.f ? a0[r] : 0.f;
    float v1 = a1[r] > 0.f ? a1[r] : 0.f;
    if (EPI == 1) {
      v0 += red4(cat, cs, rr, cc);
      v1 += red4(cat + STRIP, cs, rr, cc);
    }
    if (EPI <= 1) {
      splitw(dst,         rr * ds + colb + cc, dlo, v0);
      splitw(dst + STRIP, rr * ds + colb + cc, dlo, v1);
    } else {
      gout[(size_t)(row0 + rr) * 32 + cc]      = v0;
      gout[(size_t)(row0 + 16 + rr) * 32 + cc] = v1;
    }
  }
}

// One layer, one ct tile for this wave. A loaded just-in-time per kt; kt=0 B comes
// from the cross-barrier prefetch registers (pbh/pbl).
template<int KT, int EPI>
__device__ __forceinline__ void layerW(
    const h16* __restrict__ asrc, int as,
    const h16* __restrict__ wp, int foff, int ct, int lane,
    half8 pbh, half8 pbl,
    h16* dst, int ds, int colb, const h16* cat, int cs,
    float* __restrict__ gout, int row0)
{
  const int l15 = lane & 15, quad = lane >> 4;
  const int abase = l15 * as + quad * 8;
  const int alo = 16 * as;
  f32x4 a0 = {0.f,0.f,0.f,0.f}, a1 = {0.f,0.f,0.f,0.f};
#pragma unroll
  for (int kt = 0; kt < KT; ++kt) {
    half8 bhv, blv;
    if (kt == 0) { bhv = pbh; blv = pbl; }
    else {
      const h16* fp = wp + (((size_t)(foff + ct * KT + kt)) * 64 + lane) * 16;
      bhv = *(const half8*)fp;
      blv = *(const half8*)(fp + 8);
    }
    half8 ah0 = *(const half8*)(asrc + abase + kt * 32);
    half8 al0 = *(const half8*)(asrc + alo + abase + kt * 32);
    half8 ah1 = *(const half8*)(asrc + STRIP + abase + kt * 32);
    half8 al1 = *(const half8*)(asrc + STRIP + alo + abase + kt * 32);
    a0 = MFMA16(al0, bhv, a0); a0 = MFMA16(ah0, blv, a0); a0 = MFMA16(ah0, bhv, a0);
    a1 = MFMA16(al1, bhv, a1); a1 = MFMA16(ah1, blv, a1); a1 = MFMA16(ah1, bhv, a1);
  }
  epilogue<EPI>(a0, a1, ct, lane, dst, ds, colb, cat, cs, gout, row0);
}

// prefetch next layer's kt=0 fragpair into pbh/pbl
#define PFB(FOFF, CT_, KT_)                                                       \
  do { const h16* _fp = wp + (((size_t)((FOFF) + (CT_) * (KT_))) * 64 + lane) * 16; \
       pbh = *(const half8*)_fp; pbl = *(const half8*)(_fp + 8); } while (0)

__global__ __launch_bounds__(512, 4) void backbone(
    const float* __restrict__ feat, const h16* __restrict__ wp, float* __restrict__ out)
{
  __shared__ h16 lds[2 * STRIP];   // 65536 B, shared by the block's 8 waves
  const int lane = threadIdx.x & 63;
  const int wv   = threadIdx.x >> 6;     // 0..7
  const int l15 = lane & 15, quad = lane >> 4;
  const int row0 = blockIdx.x * 32;

  h16* E1 = lds;            const int SE1 = 40;
  h16* E2 = lds + 1280;     const int SE2 = 72;
  h16* CT = lds + 3584;     const int SCT = 264;
  h16* MR = lds + 12032;    const int SMR = 136;

  half8 pbh, pbl;

  // ---- S0: L0 (COT=2, waves 0-1): A from feat (K=16 pad 32) -> CT[:,0:32]
  if (wv < 2) {
    PFB(F_L0, wv, 1);
    h16 th0[8] = {0,0,0,0,0,0,0,0}, tl0[8] = {0,0,0,0,0,0,0,0};
    h16 th1[8] = {0,0,0,0,0,0,0,0}, tl1[8] = {0,0,0,0,0,0,0,0};
    if (quad < 2) {
      const float* s0 = feat + (size_t)(row0 + l15) * 16 + quad * 8;
      const float* s1 = feat + (size_t)(row0 + 16 + l15) * 16 + quad * 8;
#pragma unroll
      for (int j = 0; j < 8; ++j) {
        float v0 = s0[j], v1 = s1[j];
        h16 h0 = (h16)v0, h1 = (h16)v1;
        th0[j] = h0; tl0[j] = (h16)(v0 - (float)h0);
        th1[j] = h1; tl1[j] = (h16)(v1 - (float)h1);
      }
    }
    half8 ah0 = *(const half8*)th0, al0 = *(const half8*)tl0;
    half8 ah1 = *(const half8*)th1, al1 = *(const half8*)tl1;
    f32x4 a0 = {0.f,0.f,0.f,0.f}, a1 = {0.f,0.f,0.f,0.f};
    a0 = MFMA16(al0, pbh, a0); a0 = MFMA16(ah0, pbl, a0); a0 = MFMA16(ah0, pbh, a0);
    a1 = MFMA16(al1, pbh, a1); a1 = MFMA16(ah1, pbl, a1); a1 = MFMA16(ah1, pbh, a1);
    epilogue<0>(a0, a1, wv, lane, CT, SCT, 0, nullptr, 0, nullptr, 0);
    PFB(F_L1, wv, 1);
  }
  LBAR();

  // ---- S1: L1 (COT=2): x0(CT) -> E1
  if (wv < 2) {
    layerW<1,0>(CT,SCT, wp, F_L1, wv, lane, pbh,pbl, E1,SE1,0, nullptr,0, nullptr,0);
  }
  if (wv < 4) PFB(F_L2, wv, 1);
  LBAR();

  // ---- S2: L2 (COT=4): e1(E1) -> E2
  if (wv < 4) {
    layerW<1,0>(E1,SE1, wp, F_L2, wv, lane, pbh,pbl, E2,SE2,0, nullptr,0, nullptr,0);
  }
  PFB(F_L3, wv, 2);
  LBAR();

  // ---- S3: L3 (COT=8): e2(E2) -> CT[:,0:128]
  layerW<2,0>(E2,SE2, wp, F_L3, wv, lane, pbh,pbl, CT,SCT,0, nullptr,0, nullptr,0);
  PFB(F_L4, wv, 4);
  LBAR();

  // ---- S4: L4 (COT=8): e3(CT[0:128]) -> CT[:,128:256]
  layerW<4,0>(CT,SCT, wp, F_L4, wv, lane, pbh,pbl, CT,SCT,128, nullptr,0, nullptr,0);
  PFB(F_L5, wv, 8);
  LBAR();

  // ---- S5: L5 (COT=8): merge3(CT[0:256]) + red -> MR[:,0:128]
  layerW<8,1>(CT,SCT, wp, F_L5, wv, lane, pbh,pbl, MR,SMR,0, CT,SCT, nullptr,0);
  if (wv < 4) PFB(F_L6, wv, 4); else PFB(F_L7, wv - 4, 2);
  LBAR();

  // ---- S6 (fused): L6 (COT=4, waves 0-3): x2(MR[0:128]) -> CT[:,0:64]
  //                  L7 (COT=4, waves 4-7): lat2(E2)      -> CT[:,64:128]
  if (wv < 4) {
    layerW<4,0>(MR,SMR, wp, F_L6, wv, lane, pbh,pbl, CT,SCT,0,  nullptr,0, nullptr,0);
  } else {
    layerW<2,0>(E2,SE2, wp, F_L7, wv - 4, lane, pbh,pbl, CT,SCT,64, nullptr,0, nullptr,0);
  }
  if (wv < 4) PFB(F_L8, wv, 4);
  LBAR();

  // ---- S7: L8 (COT=4): merge2(CT[0:128]) + red -> MR[:,0:64]
  if (wv < 4) {
    layerW<4,1>(CT,SCT, wp, F_L8, wv, lane, pbh,pbl, MR,SMR,0, CT,SCT, nullptr,0);
  }
  if (wv < 2) PFB(F_L9, wv, 2);
  else if (wv < 4) PFB(F_L10, wv - 2, 1);
  LBAR();

  // ---- S8 (fused): L9 (COT=2, waves 0-1): x1(MR[0:64]) -> CT[:,0:32]
  //                  L10 (COT=2, waves 2-3): lat1(E1)    -> CT[:,32:64]
  if (wv < 2) {
    layerW<2,0>(MR,SMR, wp, F_L9, wv, lane, pbh,pbl, CT,SCT,0,  nullptr,0, nullptr,0);
  } else if (wv < 4) {
    layerW<1,0>(E1,SE1, wp, F_L10, wv - 2, lane, pbh,pbl, CT,SCT,32, nullptr,0, nullptr,0);
  }
  if (wv < 2) PFB(F_L11, wv, 2);
  LBAR();

  // ---- S9: L11 (COT=2): merge1(CT[0:64]) + red -> MR[:,0:32]
  if (wv < 2) {
    layerW<2,1>(CT,SCT, wp, F_L11, wv, lane, pbh,pbl, MR,SMR,0, CT,SCT, nullptr,0);
    PFB(F_L12, wv, 1);
  }
  LBAR();

  // ---- S10: L12 (COT=2): out(MR[0:32]) -> global fp32 [N,32]
  if (wv < 2) {
    layerW<1,2>(MR,SMR, wp, F_L12, wv, lane, pbh,pbl, nullptr,0,0, nullptr,0, out, row0);
  }
}

extern "C" void kernel_launch(void* const* d_in, const int* in_sizes, int n_in,
                              void* d_out, int out_size, void* d_ws, size_t ws_size,
                              hipStream_t stream) {
  (void)in_sizes; (void)n_in; (void)out_size; (void)ws_size;
  u16* packed = (u16*)d_ws;   // 352256 B

  // order: in, enc1, enc2, enc3, lat3, merge3, up3, lat2, merge2, up2, lat1, merge1, up1
  hipLaunchKernelGGL(pack_w, dim3(43), dim3(256), 0, stream,
      (const float*)d_in[2],  (const float*)d_in[3],  (const float*)d_in[4],
      (const float*)d_in[5],  (const float*)d_in[8],  (const float*)d_in[11],
      (const float*)d_in[14], (const float*)d_in[7],  (const float*)d_in[10],
      (const float*)d_in[13], (const float*)d_in[6],  (const float*)d_in[9],
      (const float*)d_in[12], packed);

  hipLaunchKernelGGL(backbone, dim3(NPAIRS), dim3(512), 0, stream,
                     (const float*)d_in[0], (const h16*)packed, (float*)d_out);
}